// Round 1
// baseline (802.169 us; speedup 1.0000x reference)
//
#include <hip/hip_runtime.h>

#define BB 512
#define V0 1024
#define V1 256
#define V2 64
#define E0 8192
#define E1 2048

// ---------------- input transpose: x[B,V0,3] -> y[V0,B,3] ----------------
__global__ void k_tx(const float* __restrict__ x, float* __restrict__ y) {
    int t = blockIdx.x * 256 + threadIdx.x;
    if (t >= V0 * BB) return;
    int v = t / BB, b = t % BB;
    y[t * 3 + 0] = x[(b * V0 + v) * 3 + 0];
    y[t * 3 + 1] = x[(b * V0 + v) * 3 + 1];
    y[t * 3 + 2] = x[(b * V0 + v) * 3 + 2];
}

// ---------------- CSR build (deterministic) ----------------
__global__ void k_deg(const int* __restrict__ rows, int E, int* __restrict__ deg) {
    int t = blockIdx.x * 256 + threadIdx.x;
    if (t < E) atomicAdd(&deg[rows[t]], 1);
}

__global__ void k_scan(const int* __restrict__ deg, int* __restrict__ off, int V) {
    __shared__ int s[1024];
    int t = threadIdx.x;
    s[t] = (t < V) ? deg[t] : 0;
    __syncthreads();
    for (int d = 1; d < 1024; d <<= 1) {
        int val = (t >= d) ? s[t - d] : 0;
        __syncthreads();
        s[t] += val;
        __syncthreads();
    }
    if (t < V) off[t + 1] = s[t];
    if (t == 0) off[0] = 0;
}

// stable fill: edge e goes to off[row] + (#earlier edges with same row)
__global__ void k_fill(const int* __restrict__ rows, const int* __restrict__ cols,
                       const float* __restrict__ vals, int E,
                       const int* __restrict__ off, int* __restrict__ scol,
                       float* __restrict__ sval) {
    __shared__ int rs[256];
    int e = blockIdx.x * 256 + threadIdx.x;
    int r = (e < E) ? rows[e] : -1;
    int rank = 0;
    for (int c0 = 0; c0 <= (int)blockIdx.x; ++c0) {
        __syncthreads();
        int idx = c0 * 256 + threadIdx.x;
        rs[threadIdx.x] = (idx < E) ? rows[idx] : -2;
        __syncthreads();
        int lim = e - c0 * 256;
        if (lim > 256) lim = 256;
        for (int j = 0; j < lim; ++j) rank += (rs[j] == r) ? 1 : 0;
    }
    if (e < E) {
        int p = off[r] + rank;
        scol[p] = cols[e];
        sval[p] = vals[e];
    }
}

// ---------------- spmm: Y[v,:] = sum_e val[e] * X[col[e],:]   (rows of B*F floats) ----------------
template <int F>
__global__ void k_spmm(const float* __restrict__ X, float* __restrict__ Y,
                       const int* __restrict__ off, const int* __restrict__ scol,
                       const float* __restrict__ sval) {
    constexpr int NF4 = BB * F / 4;
    int v = blockIdx.x;
    int i4 = blockIdx.y * 256 + threadIdx.x;
    if (i4 >= NF4) return;
    int s = off[v], e = off[v + 1];
    const float4* X4 = (const float4*)X;
    float4 acc = {0.f, 0.f, 0.f, 0.f};
    for (int p = s; p < e; ++p) {
        int c = scol[p];
        float w = sval[p];
        float4 xv = X4[(size_t)c * NF4 + i4];
        acc.x += w * xv.x; acc.y += w * xv.y; acc.z += w * xv.z; acc.w += w * xv.w;
    }
    ((float4*)Y)[(size_t)v * NF4 + i4] = acc;
}

// ---------------- fused cheby conv ----------------
// out[v,b,o] = sum_f x0[v,b,f]*(W0-W2)[o,f] + x1[v,b,f]*W1[o,f] + g[v,b,f]*(2*W2)[o,f]
// where g = L x1 gathered on the fly. W[o, f*3+kk] layout per reference.
template <int F, int FOUT>
__global__ __launch_bounds__(256) void k_cheby(
    const float* __restrict__ x0, const float* __restrict__ x1,
    const float* __restrict__ W, const float* __restrict__ bias,
    float* __restrict__ out,
    const int* __restrict__ off, const int* __restrict__ scol,
    const float* __restrict__ sval) {
    constexpr int J = 3 * F;
    __shared__ float Wl[J * FOUT];  // [0..F*FOUT)=Wa, then Wb, then Wc
    const int v = blockIdx.x;
    const int b = blockIdx.y * 256 + threadIdx.x;
    for (int i = threadIdx.x; i < F * FOUT; i += 256) {
        int f = i / FOUT, o = i % FOUT;
        float w0 = W[o * J + f * 3 + 0];
        float w1 = W[o * J + f * 3 + 1];
        float w2 = W[o * J + f * 3 + 2];
        Wl[i] = w0 - w2;
        Wl[F * FOUT + i] = w1;
        Wl[2 * F * FOUT + i] = 2.f * w2;
    }
    __syncthreads();

    float acc[FOUT];
#pragma unroll
    for (int o = 0; o < FOUT; ++o) acc[o] = bias[o];

    const float* x0r = x0 + (size_t)(v * BB + b) * F;
    const float* x1r = x1 + (size_t)(v * BB + b) * F;

    if constexpr (F % 4 == 0) {
        const float4* x0r4 = (const float4*)x0r;
        const float4* x1r4 = (const float4*)x1r;
        for (int fi = 0; fi < F / 4; ++fi) {
            float4 a = x0r4[fi];
            float4 c = x1r4[fi];
            float as[4] = {a.x, a.y, a.z, a.w};
            float cs[4] = {c.x, c.y, c.z, c.w};
#pragma unroll
            for (int q = 0; q < 4; ++q) {
                int f = fi * 4 + q;
#pragma unroll
                for (int o = 0; o < FOUT; ++o)
                    acc[o] += as[q] * Wl[f * FOUT + o] + cs[q] * Wl[(F + f) * FOUT + o];
            }
        }
        float x2a[F];
#pragma unroll
        for (int f = 0; f < F; ++f) x2a[f] = 0.f;
        const int s = off[v], e = off[v + 1];
        for (int p = s; p < e; ++p) {
            const int cc = scol[p];
            const float w = sval[p];
            const float4* xr4 = (const float4*)(x1 + (size_t)(cc * BB + b) * F);
#pragma unroll
            for (int fi = 0; fi < F / 4; ++fi) {
                float4 xv = xr4[fi];
                x2a[4 * fi + 0] += w * xv.x;
                x2a[4 * fi + 1] += w * xv.y;
                x2a[4 * fi + 2] += w * xv.z;
                x2a[4 * fi + 3] += w * xv.w;
            }
        }
#pragma unroll
        for (int f = 0; f < F; ++f) {
#pragma unroll
            for (int o = 0; o < FOUT; ++o)
                acc[o] += x2a[f] * Wl[(2 * F + f) * FOUT + o];
        }
    } else {
        float x2a[F];
#pragma unroll
        for (int f = 0; f < F; ++f) x2a[f] = 0.f;
#pragma unroll
        for (int f = 0; f < F; ++f) {
            float a = x0r[f], c = x1r[f];
#pragma unroll
            for (int o = 0; o < FOUT; ++o)
                acc[o] += a * Wl[f * FOUT + o] + c * Wl[(F + f) * FOUT + o];
        }
        const int s = off[v], e = off[v + 1];
        for (int p = s; p < e; ++p) {
            int cc = scol[p];
            float w = sval[p];
            const float* xr = x1 + (size_t)(cc * BB + b) * F;
#pragma unroll
            for (int f = 0; f < F; ++f) x2a[f] += w * xr[f];
        }
#pragma unroll
        for (int f = 0; f < F; ++f) {
#pragma unroll
            for (int o = 0; o < FOUT; ++o)
                acc[o] += x2a[f] * Wl[(2 * F + f) * FOUT + o];
        }
    }

    float* outr = out + (size_t)(v * BB + b) * FOUT;
#pragma unroll
    for (int oi = 0; oi < FOUT / 4; ++oi) {
        float4 st = {acc[4 * oi], acc[4 * oi + 1], acc[4 * oi + 2], acc[4 * oi + 3]};
        ((float4*)outr)[oi] = st;
    }
}

// ---------------- max-pool over vertex groups of 4 ----------------
template <int F, int VIN>
__global__ void k_pool(const float* __restrict__ X, float* __restrict__ Y) {
    constexpr int NF4 = BB * F / 4;
    constexpr int TOT = (VIN / 4) * NF4;
    int t = blockIdx.x * 256 + threadIdx.x;
    if (t >= TOT) return;
    int vp = t / NF4, j = t % NF4;
    const float4* X4 = (const float4*)X;
    float4 a = X4[(size_t)(vp * 4 + 0) * NF4 + j];
    float4 b = X4[(size_t)(vp * 4 + 1) * NF4 + j];
    float4 c = X4[(size_t)(vp * 4 + 2) * NF4 + j];
    float4 d = X4[(size_t)(vp * 4 + 3) * NF4 + j];
    float4 m;
    m.x = fmaxf(fmaxf(a.x, b.x), fmaxf(c.x, d.x));
    m.y = fmaxf(fmaxf(a.y, b.y), fmaxf(c.y, d.y));
    m.z = fmaxf(fmaxf(a.z, b.z), fmaxf(c.z, d.z));
    m.w = fmaxf(fmaxf(a.w, b.w), fmaxf(c.w, d.w));
    ((float4*)Y)[t] = m;
}

// ---------------- fc input transpose: [V2,B,64] -> [B, V2*64] ----------------
__global__ void k_fct(const float* __restrict__ X, float* __restrict__ Y) {
    int t = blockIdx.x * 256 + threadIdx.x;  // over BB*1024 float4s
    if (t >= BB * 1024) return;
    int b = t / 1024, k4 = t % 1024;
    int v = k4 >> 4, f4i = k4 & 15;
    ((float4*)Y)[t] = ((const float4*)X)[(size_t)(v * BB + b) * 16 + f4i];
}

// ---------------- FC1: C[512,512] = A[512,4096] * W[512,4096]^T, split-K=16 ----------------
__global__ __launch_bounds__(256) void k_fc1(const float* __restrict__ A,
                                             const float* __restrict__ W,
                                             float* __restrict__ part) {
    __shared__ float As[16][128];
    __shared__ float Bs[16][128];
    const int tid = threadIdx.x;
    const int bm = blockIdx.x, bn = blockIdx.y, bz = blockIdx.z;
    const int m0 = (tid >> 4) << 3;
    const int n0 = (tid & 15) << 3;
    float acc[8][8];
#pragma unroll
    for (int i = 0; i < 8; ++i)
#pragma unroll
        for (int j = 0; j < 8; ++j) acc[i][j] = 0.f;
    const int r = tid >> 1;
    const int c8 = (tid & 1) << 3;
    const float* Ar = A + (size_t)(bm * 128 + r) * 4096 + bz * 256 + c8;
    const float* Wr = W + (size_t)(bn * 128 + r) * 4096 + bz * 256 + c8;
    for (int kt = 0; kt < 256; kt += 16) {
        float4 a0 = *(const float4*)(Ar + kt);
        float4 a1 = *(const float4*)(Ar + kt + 4);
        float4 w0 = *(const float4*)(Wr + kt);
        float4 w1 = *(const float4*)(Wr + kt + 4);
        __syncthreads();
        As[c8 + 0][r] = a0.x; As[c8 + 1][r] = a0.y; As[c8 + 2][r] = a0.z; As[c8 + 3][r] = a0.w;
        As[c8 + 4][r] = a1.x; As[c8 + 5][r] = a1.y; As[c8 + 6][r] = a1.z; As[c8 + 7][r] = a1.w;
        Bs[c8 + 0][r] = w0.x; Bs[c8 + 1][r] = w0.y; Bs[c8 + 2][r] = w0.z; Bs[c8 + 3][r] = w0.w;
        Bs[c8 + 4][r] = w1.x; Bs[c8 + 5][r] = w1.y; Bs[c8 + 6][r] = w1.z; Bs[c8 + 7][r] = w1.w;
        __syncthreads();
#pragma unroll
        for (int k = 0; k < 16; ++k) {
            float am[8], bn_[8];
            *(float4*)&am[0] = *(const float4*)&As[k][m0];
            *(float4*)&am[4] = *(const float4*)&As[k][m0 + 4];
            *(float4*)&bn_[0] = *(const float4*)&Bs[k][n0];
            *(float4*)&bn_[4] = *(const float4*)&Bs[k][n0 + 4];
#pragma unroll
            for (int i = 0; i < 8; ++i)
#pragma unroll
                for (int j = 0; j < 8; ++j) acc[i][j] += am[i] * bn_[j];
        }
    }
    float* P = part + ((size_t)bz * 512 + bm * 128 + m0) * 512 + bn * 128 + n0;
#pragma unroll
    for (int i = 0; i < 8; ++i) {
        float4 s0 = {acc[i][0], acc[i][1], acc[i][2], acc[i][3]};
        float4 s1 = {acc[i][4], acc[i][5], acc[i][6], acc[i][7]};
        *(float4*)(P + i * 512) = s0;
        *(float4*)(P + i * 512 + 4) = s1;
    }
}

__global__ void k_fc1red(const float* __restrict__ part, const float* __restrict__ bias,
                         float* __restrict__ out) {
    int t = blockIdx.x * 256 + threadIdx.x;  // 512*512
    float s = bias[t & 511];
#pragma unroll
    for (int z = 0; z < 16; ++z) s += part[(size_t)z * 262144 + t];
    out[t] = s;
}

// ---------------- FC2: out[512,63] ----------------
__global__ void k_fc2(const float* __restrict__ X, const float* __restrict__ W,
                      const float* __restrict__ bias, float* __restrict__ out) {
    int b = blockIdx.x, c = threadIdx.x;
    if (c >= 63) return;
    const float4* xr = (const float4*)(X + b * 512);
    const float4* wr = (const float4*)(W + c * 512);
    float s = 0.f;
    for (int k = 0; k < 128; ++k) {
        float4 xv = xr[k], wv = wr[k];
        s += xv.x * wv.x + xv.y * wv.y + xv.z * wv.z + xv.w * wv.w;
    }
    out[b * 63 + c] = s + bias[c];
}

extern "C" void kernel_launch(void* const* d_in, const int* in_sizes, int n_in,
                              void* d_out, int out_size, void* d_ws, size_t ws_size,
                              hipStream_t stream) {
    const float* x = (const float*)d_in[0];
    const int* rows0 = (const int*)d_in[1];
    const int* cols0 = (const int*)d_in[2];
    const float* vals0 = (const float*)d_in[3];
    const int* rows1 = (const int*)d_in[4];
    const int* cols1 = (const int*)d_in[5];
    const float* vals1 = (const float*)d_in[6];
    const float* W0 = (const float*)d_in[7];  const float* b0 = (const float*)d_in[8];
    const float* W1 = (const float*)d_in[9];  const float* b1 = (const float*)d_in[10];
    const float* W2 = (const float*)d_in[11]; const float* b2 = (const float*)d_in[12];
    const float* W3 = (const float*)d_in[13]; const float* b3 = (const float*)d_in[14];
    const float* fcW1 = (const float*)d_in[15]; const float* fcb1 = (const float*)d_in[16];
    const float* fcW2 = (const float*)d_in[17]; const float* fcb2 = (const float*)d_in[18];
    float* out = (float*)d_out;

    float* wsf = (float*)d_ws;
    // CSR region (aliased ints/floats), 65536 floats
    int* off0 = (int*)(wsf + 0);          // 1025
    int* scol0 = (int*)(wsf + 2048);      // 8192
    float* sval0 = wsf + 10240;           // 8192
    int* off1 = (int*)(wsf + 18432);      // 257
    int* scol1 = (int*)(wsf + 20480);     // 2048
    float* sval1 = wsf + 22528;           // 2048
    int* deg0 = (int*)(wsf + 24576);      // 1024
    int* deg1 = (int*)(wsf + 25600);      // 256

    float* TX0 = wsf + 65536;             // 1,572,864  [V0,B,3]
    float* TX1 = TX0 + 1572864;           // 1,572,864
    float* A0p = wsf + 3211264;           // 16,777,216 [V0,B,32]
    float* A1p = A0p + 16777216;
    float* A2p = A1p + 16777216;
    float* P1 = A2p + 16777216;           // 4,194,304  [V1,B,32]
    // reuse:
    float* P2 = TX0;                      // 2,097,152  [V2,B,64]
    float* FCB = A1p;                     // 2,097,152  [B,4096]
    float* PART = A2p;                    // 4,194,304  [16,512,512]
    float* FC1O = A0p;                    // 262,144    [512,512]
    // total footprint: 57,737,216 floats = ~231 MB
    (void)in_sizes; (void)n_in; (void)out_size; (void)ws_size;

    hipMemsetAsync(wsf, 0, 65536 * 4, stream);
    k_deg<<<E0 / 256, 256, 0, stream>>>(rows0, E0, deg0);
    k_deg<<<E1 / 256, 256, 0, stream>>>(rows1, E1, deg1);
    k_scan<<<1, 1024, 0, stream>>>(deg0, off0, V0);
    k_scan<<<1, 1024, 0, stream>>>(deg1, off1, V1);
    k_fill<<<E0 / 256, 256, 0, stream>>>(rows0, cols0, vals0, E0, off0, scol0, sval0);
    k_fill<<<E1 / 256, 256, 0, stream>>>(rows1, cols1, vals1, E1, off1, scol1, sval1);

    k_tx<<<(V0 * BB) / 256, 256, 0, stream>>>(x, TX0);

    // block 1 (graph 0)
    k_spmm<3><<<dim3(V0, 2), 256, 0, stream>>>(TX0, TX1, off0, scol0, sval0);
    k_cheby<3, 32><<<dim3(V0, 2), 256, 0, stream>>>(TX0, TX1, W0, b0, A0p, off0, scol0, sval0);
    k_spmm<32><<<dim3(V0, 16), 256, 0, stream>>>(A0p, A1p, off0, scol0, sval0);
    k_cheby<32, 32><<<dim3(V0, 2), 256, 0, stream>>>(A0p, A1p, W1, b1, A2p, off0, scol0, sval0);
    k_pool<32, V0><<<(V0 / 4) * BB * 32 / 4 / 256, 256, 0, stream>>>(A2p, P1);

    // block 2 (graph 1)
    k_spmm<32><<<dim3(V1, 16), 256, 0, stream>>>(P1, A0p, off1, scol1, sval1);
    k_cheby<32, 64><<<dim3(V1, 2), 256, 0, stream>>>(P1, A0p, W2, b2, A1p, off1, scol1, sval1);
    k_spmm<64><<<dim3(V1, 32), 256, 0, stream>>>(A1p, A2p, off1, scol1, sval1);
    k_cheby<64, 64><<<dim3(V1, 2), 256, 0, stream>>>(A1p, A2p, W3, b3, A0p, off1, scol1, sval1);
    k_pool<64, V1><<<(V1 / 4) * BB * 64 / 4 / 256, 256, 0, stream>>>(A0p, P2);

    // head
    k_fct<<<(BB * 1024) / 256, 256, 0, stream>>>(P2, FCB);
    k_fc1<<<dim3(4, 4, 16), 256, 0, stream>>>(FCB, fcW1, PART);
    k_fc1red<<<1024, 256, 0, stream>>>(PART, fcb1, FC1O);
    k_fc2<<<BB, 64, 0, stream>>>(FC1O, fcW2, fcb2, out);
}